// Round 1
// baseline (603.333 us; speedup 1.0000x reference)
//
#include <hip/hip_runtime.h>
#include <stdint.h>

// ---------- types ----------
typedef __attribute__((ext_vector_type(4))) float f32x4;
typedef __attribute__((ext_vector_type(8))) short short8;

#define MFMA_BF16(a, b, c) __builtin_amdgcn_mfma_f32_16x16x32_bf16(a, b, c, 0, 0, 0)

#define GLD16(gp, lp)                                                          \
  __builtin_amdgcn_global_load_lds(                                            \
      (const __attribute__((address_space(1))) void*)(gp),                     \
      (__attribute__((address_space(3))) void*)(lp), 16, 0, 0)

__device__ __forceinline__ short f2bf(float f) {
  union { float f; uint32_t u; } v; v.f = f;
  uint32_t r = (v.u + 0x7FFFu + ((v.u >> 16) & 1u)) >> 16;
  return (short)r;
}
__device__ __forceinline__ float bf2f(short s) {
  union { uint32_t u; float f; } v; v.u = ((uint32_t)(uint16_t)s) << 16;
  return v.f;
}

// ---------- elementwise split / cast ----------
__global__ __launch_bounds__(256) void split_pair(const float* __restrict__ src,
                                                  short* __restrict__ dh,
                                                  short* __restrict__ dl, int n) {
  int i = blockIdx.x * 256 + threadIdx.x;
  if (i < n) {
    float v = src[i];
    short hv = f2bf(v);
    dh[i] = hv;
    dl[i] = f2bf(v - bf2f(hv));
  }
}

__global__ __launch_bounds__(256) void cast_bf16(const float* __restrict__ src,
                                                 short* __restrict__ d, int n) {
  int i = blockIdx.x * 256 + threadIdx.x;
  if (i < n) d[i] = f2bf(src[i]);
}

// ---------- fused QKV projection GEMM ----------
// C[m,n] = sum_k X[m,k] * W[n,k],  M=8192, N=3072 (Q|K|V), K=1024
// 3-term split-bf16. Epilogue scatters to Q_hi/Q_lo/K_hi/K_lo/V in [B,H,S,64].
__global__ __launch_bounds__(256) void gemm_proj(
    const short* __restrict__ Xh, const short* __restrict__ Xl,
    const short* __restrict__ Wh, const short* __restrict__ Wl,
    short* __restrict__ Qh, short* __restrict__ Ql,
    short* __restrict__ Kh, short* __restrict__ Kl,
    short* __restrict__ Vb) {
  __shared__ short sAh[128 * 32], sAl[128 * 32], sBh[128 * 32], sBl[128 * 32];
  const int tid = threadIdx.x, lane = tid & 63, w = tid >> 6;
  const int wr = w >> 1, wc = w & 1;
  const int g = lane >> 4, c = lane & 15;
  const int m0 = blockIdx.y * 128, n0 = blockIdx.x * 128;

  f32x4 acc[4][4];
#pragma unroll
  for (int i = 0; i < 4; i++)
#pragma unroll
    for (int j = 0; j < 4; j++) acc[i][j] = (f32x4){0.f, 0.f, 0.f, 0.f};

  for (int ks = 0; ks < 32; ks++) {
    const int k0 = ks * 32;
    __syncthreads();
#pragma unroll
    for (int i = 0; i < 2; i++) {
      const int chunk = i * 256 + w * 64 + lane;
      const int row = chunk >> 2;
      const int col = (chunk & 3) * 8;
      const size_t aoff = (size_t)(m0 + row) * 1024 + k0 + col;
      const size_t boff = (size_t)(n0 + row) * 1024 + k0 + col;
      const int ldsoff = (i * 256 + w * 64) * 16;
      GLD16(Xh + aoff, (char*)sAh + ldsoff);
      GLD16(Xl + aoff, (char*)sAl + ldsoff);
      GLD16(Wh + boff, (char*)sBh + ldsoff);
      GLD16(Wl + boff, (char*)sBl + ldsoff);
    }
    asm volatile("s_waitcnt vmcnt(0)" ::: "memory");
    __syncthreads();

    short8 ah[4], al[4], bh[4], bl[4];
#pragma unroll
    for (int i = 0; i < 4; i++) {
      const int ar = (wr * 64 + i * 16 + c) * 32 + g * 8;
      const int br = (wc * 64 + i * 16 + c) * 32 + g * 8;
      ah[i] = *(const short8*)&sAh[ar];
      al[i] = *(const short8*)&sAl[ar];
      bh[i] = *(const short8*)&sBh[br];
      bl[i] = *(const short8*)&sBl[br];
    }
#pragma unroll
    for (int i = 0; i < 4; i++)
#pragma unroll
      for (int j = 0; j < 4; j++) {
        acc[i][j] = MFMA_BF16(ah[i], bh[j], acc[i][j]);
        acc[i][j] = MFMA_BF16(ah[i], bl[j], acc[i][j]);
        acc[i][j] = MFMA_BF16(al[i], bh[j], acc[i][j]);
      }
  }

  const int section = n0 >> 10;  // 0=Q 1=K 2=V
#pragma unroll
  for (int i = 0; i < 4; i++)
#pragma unroll
    for (int j = 0; j < 4; j++)
#pragma unroll
      for (int r = 0; r < 4; r++) {
        const float v = acc[i][j][r];
        const int m = m0 + wr * 64 + i * 16 + g * 4 + r;
        const int n = n0 + wc * 64 + j * 16 + c;
        const int b = m >> 11, s = m & 2047;
        const int nn = n & 1023;
        const int hh = nn >> 6, d = nn & 63;
        const size_t off = ((size_t)(b * 16 + hh) * 2048 + s) * 64 + d;
        if (section == 0) {
          short hv = f2bf(v);
          Qh[off] = hv;
          Ql[off] = f2bf(v - bf2f(hv));
        } else if (section == 1) {
          short hv = f2bf(v);
          Kh[off] = hv;
          Kl[off] = f2bf(v - bf2f(hv));
        } else {
          Vb[off] = f2bf(v);
        }
      }
}

// ---------- flash attention ----------
// grid (32 qblocks, 64 bh). block = 256 (4 waves x 16 q-rows).
__global__ __launch_bounds__(256) void attn_kernel(
    const short* __restrict__ Qh, const short* __restrict__ Ql,
    const short* __restrict__ Kh, const short* __restrict__ Kl,
    const short* __restrict__ Vb, short* __restrict__ Z) {
  __shared__ short sKh[64 * 64], sKl[64 * 64], sV[64 * 64];
  __shared__ short sP[4][16 * 64];
  const int tid = threadIdx.x, lane = tid & 63, w = tid >> 6;
  const int g = lane >> 4, c = lane & 15;
  const int qblk = blockIdx.x, bh = blockIdx.y;
  const int b = bh >> 4, h = bh & 15;
  const size_t base = (size_t)bh * (2048 * 64);

  // Q fragments (held for whole kernel)
  short8 qh[2], ql[2];
  {
    const int qrow = qblk * 64 + w * 16 + c;
#pragma unroll
    for (int cc = 0; cc < 2; cc++) {
      const size_t off = base + (size_t)qrow * 64 + cc * 32 + g * 8;
      qh[cc] = *(const short8*)(Qh + off);
      ql[cc] = *(const short8*)(Ql + off);
    }
  }

  f32x4 zacc[4];
  float m_run[4], l_run[4];
#pragma unroll
  for (int dt = 0; dt < 4; dt++) zacc[dt] = (f32x4){0.f, 0.f, 0.f, 0.f};
#pragma unroll
  for (int r = 0; r < 4; r++) { m_run[r] = -INFINITY; l_run[r] = 0.f; }

  for (int kt = 0; kt < 32; kt++) {
    __syncthreads();
    const int kv0 = kt * 64;
#pragma unroll
    for (int i = 0; i < 2; i++) {
      const int chunk = i * 256 + w * 64 + lane;
      const int row = chunk >> 3;
      const int colc = chunk & 7;
      const size_t goff = base + (size_t)(kv0 + row) * 64 + colc * 8;
      const int ldsoff = (i * 256 + w * 64) * 16;
      GLD16(Kh + goff, (char*)sKh + ldsoff);
      GLD16(Kl + goff, (char*)sKl + ldsoff);
      GLD16(Vb + goff, (char*)sV + ldsoff);
    }
    asm volatile("s_waitcnt vmcnt(0)" ::: "memory");
    __syncthreads();

    // QK^T (3-term split) -> 16x64 scores per wave
    f32x4 sacc[4];
#pragma unroll
    for (int t = 0; t < 4; t++) sacc[t] = (f32x4){0.f, 0.f, 0.f, 0.f};
#pragma unroll
    for (int cc = 0; cc < 2; cc++)
#pragma unroll
      for (int t = 0; t < 4; t++) {
        const int kr = (t * 16 + c) * 64 + cc * 32 + g * 8;
        short8 kh8 = *(const short8*)&sKh[kr];
        short8 kl8 = *(const short8*)&sKl[kr];
        sacc[t] = MFMA_BF16(qh[cc], kh8, sacc[t]);
        sacc[t] = MFMA_BF16(qh[cc], kl8, sacc[t]);
        sacc[t] = MFMA_BF16(ql[cc], kh8, sacc[t]);
      }

    // mask, scale, online softmax
    float lg[4][4];  // [t][r]
    float tmax[4];
#pragma unroll
    for (int r = 0; r < 4; r++) tmax[r] = -INFINITY;
#pragma unroll
    for (int t = 0; t < 4; t++)
#pragma unroll
      for (int r = 0; r < 4; r++) {
        float s = sacc[t][r];
        if (s == 0.0f) s = -1e9f;   // reference's zero-value mask
        s *= 8.0f;                  // * sqrt(d_k)
        lg[t][r] = s;
        tmax[r] = fmaxf(tmax[r], s);
      }
#pragma unroll
    for (int r = 0; r < 4; r++) {
#pragma unroll
      for (int off = 8; off >= 1; off >>= 1)
        tmax[r] = fmaxf(tmax[r], __shfl_xor(tmax[r], off, 16));
    }
    float scale[4], rsum[4];
#pragma unroll
    for (int r = 0; r < 4; r++) {
      const float mnew = fmaxf(m_run[r], tmax[r]);
      scale[r] = __expf(m_run[r] - mnew);
      m_run[r] = mnew;
      float rs = 0.f;
#pragma unroll
      for (int t = 0; t < 4; t++) {
        lg[t][r] = __expf(lg[t][r] - mnew);
        rs += lg[t][r];
      }
      rsum[r] = rs;
    }
#pragma unroll
    for (int r = 0; r < 4; r++) {
#pragma unroll
      for (int off = 8; off >= 1; off >>= 1)
        rsum[r] += __shfl_xor(rsum[r], off, 16);
      l_run[r] = l_run[r] * scale[r] + rsum[r];
    }
#pragma unroll
    for (int dt = 0; dt < 4; dt++)
#pragma unroll
      for (int r = 0; r < 4; r++) zacc[dt][r] *= scale[r];

    // write P (bf16) to per-wave LDS
#pragma unroll
    for (int t = 0; t < 4; t++)
#pragma unroll
      for (int r = 0; r < 4; r++)
        sP[w][(g * 4 + r) * 64 + t * 16 + c] = f2bf(lg[t][r]);
    asm volatile("s_waitcnt lgkmcnt(0)" ::: "memory");

    // PV
#pragma unroll
    for (int cc = 0; cc < 2; cc++) {
      short8 pa = *(const short8*)&sP[w][c * 64 + cc * 32 + g * 8];
#pragma unroll
      for (int dt = 0; dt < 4; dt++) {
        short8 vb;
#pragma unroll
        for (int j = 0; j < 8; j++)
          vb[j] = sV[(cc * 32 + g * 8 + j) * 64 + dt * 16 + c];
        zacc[dt] = MFMA_BF16(pa, vb, zacc[dt]);
      }
    }
  }

  // epilogue: normalize, store Z[b*2048+q][h*64+d] bf16
  float inv[4];
#pragma unroll
  for (int r = 0; r < 4; r++) inv[r] = l_run[r] > 0.f ? 1.0f / l_run[r] : 0.f;
#pragma unroll
  for (int dt = 0; dt < 4; dt++)
#pragma unroll
    for (int r = 0; r < 4; r++) {
      const int qg = qblk * 64 + w * 16 + g * 4 + r;
      const int col = h * 64 + dt * 16 + c;
      Z[(size_t)(b * 2048 + qg) * 1024 + col] = f2bf(zacc[dt][r] * inv[r]);
    }
}

// ---------- output projection GEMM ----------
// out[m,n] = sum_k Z[m,k]*Wo[n,k] + bo[n], M=8192, N=1024, K=1024, fp32 out
__global__ __launch_bounds__(256) void gemm_out(
    const short* __restrict__ Zb, const short* __restrict__ Wob,
    const float* __restrict__ bo, float* __restrict__ out) {
  __shared__ short sA[128 * 32], sB[128 * 32];
  const int tid = threadIdx.x, lane = tid & 63, w = tid >> 6;
  const int wr = w >> 1, wc = w & 1;
  const int g = lane >> 4, c = lane & 15;
  const int m0 = blockIdx.y * 128, n0 = blockIdx.x * 128;

  f32x4 acc[4][4];
#pragma unroll
  for (int i = 0; i < 4; i++)
#pragma unroll
    for (int j = 0; j < 4; j++) acc[i][j] = (f32x4){0.f, 0.f, 0.f, 0.f};

  for (int ks = 0; ks < 32; ks++) {
    const int k0 = ks * 32;
    __syncthreads();
#pragma unroll
    for (int i = 0; i < 2; i++) {
      const int chunk = i * 256 + w * 64 + lane;
      const int row = chunk >> 2;
      const int col = (chunk & 3) * 8;
      const size_t aoff = (size_t)(m0 + row) * 1024 + k0 + col;
      const size_t boff = (size_t)(n0 + row) * 1024 + k0 + col;
      const int ldsoff = (i * 256 + w * 64) * 16;
      GLD16(Zb + aoff, (char*)sA + ldsoff);
      GLD16(Wob + boff, (char*)sB + ldsoff);
    }
    asm volatile("s_waitcnt vmcnt(0)" ::: "memory");
    __syncthreads();

    short8 a[4], b8[4];
#pragma unroll
    for (int i = 0; i < 4; i++) {
      a[i] = *(const short8*)&sA[(wr * 64 + i * 16 + c) * 32 + g * 8];
      b8[i] = *(const short8*)&sB[(wc * 64 + i * 16 + c) * 32 + g * 8];
    }
#pragma unroll
    for (int i = 0; i < 4; i++)
#pragma unroll
      for (int j = 0; j < 4; j++) acc[i][j] = MFMA_BF16(a[i], b8[j], acc[i][j]);
  }

#pragma unroll
  for (int i = 0; i < 4; i++)
#pragma unroll
    for (int j = 0; j < 4; j++)
#pragma unroll
      for (int r = 0; r < 4; r++) {
        const int m = m0 + wr * 64 + i * 16 + g * 4 + r;
        const int n = n0 + wc * 64 + j * 16 + c;
        out[(size_t)m * 1024 + n] = acc[i][j][r] + bo[n];
      }
}

// ---------- host ----------
extern "C" void kernel_launch(void* const* d_in, const int* in_sizes, int n_in,
                              void* d_out, int out_size, void* d_ws, size_t ws_size,
                              hipStream_t stream) {
  const float* x  = (const float*)d_in[0];
  const float* Wq = (const float*)d_in[1];
  const float* Wk = (const float*)d_in[2];
  const float* Wv = (const float*)d_in[3];
  const float* Wo = (const float*)d_in[4];
  const float* bo = (const float*)d_in[5];
  float* out = (float*)d_out;

  const size_t NX = 8388608;   // B*S*D_MODEL
  const size_t NW = 1048576;   // per-projection weight elements
  const size_t NQ = 8388608;   // B*H*S*D_K

  char* p = (char*)d_ws;
  auto take = [&](size_t bytes) -> char* {
    char* r = p;
    p += (bytes + 255) & ~(size_t)255;
    return r;
  };
  short* xh  = (short*)take(NX * 2);
  short* xl  = (short*)take(NX * 2);
  short* Wh  = (short*)take(3 * NW * 2);
  short* Wl  = (short*)take(3 * NW * 2);
  short* Woh = (short*)take(NW * 2);
  short* Qh  = (short*)take(NQ * 2);
  short* Ql  = (short*)take(NQ * 2);
  short* Kh  = (short*)take(NQ * 2);
  short* Kl  = (short*)take(NQ * 2);
  short* Vb  = (short*)take(NQ * 2);
  short* Zb  = (short*)take(NQ * 2);

  split_pair<<<dim3((int)(NX / 256)), 256, 0, stream>>>(x, xh, xl, (int)NX);
  split_pair<<<dim3((int)(NW / 256)), 256, 0, stream>>>(Wq, Wh, Wl, (int)NW);
  split_pair<<<dim3((int)(NW / 256)), 256, 0, stream>>>(Wk, Wh + NW, Wl + NW, (int)NW);
  split_pair<<<dim3((int)(NW / 256)), 256, 0, stream>>>(Wv, Wh + 2 * NW, Wl + 2 * NW, (int)NW);
  cast_bf16<<<dim3((int)(NW / 256)), 256, 0, stream>>>(Wo, Woh, (int)NW);

  gemm_proj<<<dim3(24, 64), 256, 0, stream>>>(xh, xl, Wh, Wl, Qh, Ql, Kh, Kl, Vb);
  attn_kernel<<<dim3(32, 64), 256, 0, stream>>>(Qh, Ql, Kh, Kl, Vb, Zb);
  gemm_out<<<dim3(8, 64), 256, 0, stream>>>(Zb, Woh, bo, out);
}

// Round 2
// 474.988 us; speedup vs baseline: 1.2702x; 1.2702x over previous
//
#include <hip/hip_runtime.h>
#include <stdint.h>

// ---------- types ----------
typedef __attribute__((ext_vector_type(4))) float f32x4;
typedef __attribute__((ext_vector_type(8))) short short8;

#define MFMA_BF16(a, b, c) __builtin_amdgcn_mfma_f32_16x16x32_bf16(a, b, c, 0, 0, 0)

#define GLD16(gp, lp)                                                          \
  __builtin_amdgcn_global_load_lds(                                            \
      (const __attribute__((address_space(1))) void*)(gp),                     \
      (__attribute__((address_space(3))) void*)(lp), 16, 0, 0)

__device__ __forceinline__ short f2bf(float f) {
  union { float f; uint32_t u; } v; v.f = f;
  uint32_t r = (v.u + 0x7FFFu + ((v.u >> 16) & 1u)) >> 16;
  return (short)r;
}
__device__ __forceinline__ float bf2f(short s) {
  union { uint32_t u; float f; } v; v.u = ((uint32_t)(uint16_t)s) << 16;
  return v.f;
}

// ---------- elementwise split / cast ----------
__global__ __launch_bounds__(256) void split_pair(const float* __restrict__ src,
                                                  short* __restrict__ dh,
                                                  short* __restrict__ dl, int n) {
  int i = blockIdx.x * 256 + threadIdx.x;
  if (i < n) {
    float v = src[i];
    short hv = f2bf(v);
    dh[i] = hv;
    dl[i] = f2bf(v - bf2f(hv));
  }
}

__global__ __launch_bounds__(256) void cast_bf16(const float* __restrict__ src,
                                                 short* __restrict__ d, int n) {
  int i = blockIdx.x * 256 + threadIdx.x;
  if (i < n) d[i] = f2bf(src[i]);
}

// ---------- fused QKV projection GEMM ----------
// C[m,n] = sum_k X[m,k] * W[n,k],  M=8192, N=3072 (Q|K|V), K=1024
// 3-term split-bf16. Epilogue: Q/K -> hi/lo [B,H,S,64]; V -> TRANSPOSED [B,H,64,S].
__global__ __launch_bounds__(256) void gemm_proj(
    const short* __restrict__ Xh, const short* __restrict__ Xl,
    const short* __restrict__ Wh, const short* __restrict__ Wl,
    short* __restrict__ Qh, short* __restrict__ Ql,
    short* __restrict__ Kh, short* __restrict__ Kl,
    short* __restrict__ Vt) {
  __shared__ short sAh[128 * 32], sAl[128 * 32], sBh[128 * 32], sBl[128 * 32];
  const int tid = threadIdx.x, lane = tid & 63, w = tid >> 6;
  const int wr = w >> 1, wc = w & 1;
  const int g = lane >> 4, c = lane & 15;
  const int m0 = blockIdx.y * 128, n0 = blockIdx.x * 128;

  f32x4 acc[4][4];
#pragma unroll
  for (int i = 0; i < 4; i++)
#pragma unroll
    for (int j = 0; j < 4; j++) acc[i][j] = (f32x4){0.f, 0.f, 0.f, 0.f};

  for (int ks = 0; ks < 32; ks++) {
    const int k0 = ks * 32;
    __syncthreads();
#pragma unroll
    for (int i = 0; i < 2; i++) {
      const int chunk = i * 256 + w * 64 + lane;
      const int row = chunk >> 2;
      const int col = (chunk & 3) * 8;
      const size_t aoff = (size_t)(m0 + row) * 1024 + k0 + col;
      const size_t boff = (size_t)(n0 + row) * 1024 + k0 + col;
      const int ldsoff = (i * 256 + w * 64) * 16;
      GLD16(Xh + aoff, (char*)sAh + ldsoff);
      GLD16(Xl + aoff, (char*)sAl + ldsoff);
      GLD16(Wh + boff, (char*)sBh + ldsoff);
      GLD16(Wl + boff, (char*)sBl + ldsoff);
    }
    asm volatile("s_waitcnt vmcnt(0)" ::: "memory");
    __syncthreads();

    short8 ah[4], al[4], bh[4], bl[4];
#pragma unroll
    for (int i = 0; i < 4; i++) {
      const int ar = (wr * 64 + i * 16 + c) * 32 + g * 8;
      const int br = (wc * 64 + i * 16 + c) * 32 + g * 8;
      ah[i] = *(const short8*)&sAh[ar];
      al[i] = *(const short8*)&sAl[ar];
      bh[i] = *(const short8*)&sBh[br];
      bl[i] = *(const short8*)&sBl[br];
    }
#pragma unroll
    for (int i = 0; i < 4; i++)
#pragma unroll
      for (int j = 0; j < 4; j++) {
        acc[i][j] = MFMA_BF16(ah[i], bh[j], acc[i][j]);
        acc[i][j] = MFMA_BF16(ah[i], bl[j], acc[i][j]);
        acc[i][j] = MFMA_BF16(al[i], bh[j], acc[i][j]);
      }
  }

  const int section = n0 >> 10;  // 0=Q 1=K 2=V
#pragma unroll
  for (int i = 0; i < 4; i++)
#pragma unroll
    for (int j = 0; j < 4; j++)
#pragma unroll
      for (int r = 0; r < 4; r++) {
        const float v = acc[i][j][r];
        const int m = m0 + wr * 64 + i * 16 + g * 4 + r;
        const int n = n0 + wc * 64 + j * 16 + c;
        const int b = m >> 11, s = m & 2047;
        const int nn = n & 1023;
        const int hh = nn >> 6, d = nn & 63;
        if (section == 0) {
          const size_t off = ((size_t)(b * 16 + hh) * 2048 + s) * 64 + d;
          short hv = f2bf(v);
          Qh[off] = hv;
          Ql[off] = f2bf(v - bf2f(hv));
        } else if (section == 1) {
          const size_t off = ((size_t)(b * 16 + hh) * 2048 + s) * 64 + d;
          short hv = f2bf(v);
          Kh[off] = hv;
          Kl[off] = f2bf(v - bf2f(hv));
        } else {
          // transposed: Vt[(bh*64 + d)*2048 + s]
          Vt[((size_t)(b * 16 + hh) * 64 + d) * 2048 + s] = f2bf(v);
        }
      }
}

// ---------- flash attention ----------
// grid (32 qblocks, 64 bh). block = 256 (4 waves x 16 q-rows).
// All LDS tiles are [row][64 shorts = 8 x 16B chunks], XOR-swizzled:
//   position (row, chunk) holds data chunk (chunk ^ (row&7)).
// global_load_lds dest stays linear; the GLOBAL source address is pre-swizzled.
__global__ __launch_bounds__(256) void attn_kernel(
    const short* __restrict__ Qh, const short* __restrict__ Ql,
    const short* __restrict__ Kh, const short* __restrict__ Kl,
    const short* __restrict__ Vt, short* __restrict__ Z) {
  __shared__ short sKh[64 * 64], sKl[64 * 64], sV[64 * 64];
  __shared__ short sP[4][16 * 64];
  const int tid = threadIdx.x, lane = tid & 63, w = tid >> 6;
  const int g = lane >> 4, c = lane & 15;
  const int qblk = blockIdx.x, bh = blockIdx.y;
  const int b = bh >> 4, h = bh & 15;
  const size_t base = (size_t)bh * (2048 * 64);

  // Q fragments (held for whole kernel)
  short8 qh[2], ql[2];
  {
    const int qrow = qblk * 64 + w * 16 + c;
#pragma unroll
    for (int cc = 0; cc < 2; cc++) {
      const size_t off = base + (size_t)qrow * 64 + cc * 32 + g * 8;
      qh[cc] = *(const short8*)(Qh + off);
      ql[cc] = *(const short8*)(Ql + off);
    }
  }

  f32x4 zacc[4];
  float m_run[4], l_run[4];
#pragma unroll
  for (int dt = 0; dt < 4; dt++) zacc[dt] = (f32x4){0.f, 0.f, 0.f, 0.f};
#pragma unroll
  for (int r = 0; r < 4; r++) { m_run[r] = -INFINITY; l_run[r] = 0.f; }

  // per-thread swizzled chunk indices (chunk' = (cc*4+g) ^ (c&7))
  const int sw0 = ((0 * 4 + g) ^ (c & 7)) * 8;
  const int sw1 = ((1 * 4 + g) ^ (c & 7)) * 8;

  for (int kt = 0; kt < 32; kt++) {
    __syncthreads();
    const int kv0 = kt * 64;
#pragma unroll
    for (int i = 0; i < 2; i++) {
      const int chunk = i * 256 + w * 64 + lane;
      const int row = chunk >> 3;
      const int colg = (chunk & 7) ^ (row & 7);  // pre-swizzled global chunk
      const int ldsoff = chunk * 16;
      const size_t goffK = base + (size_t)(kv0 + row) * 64 + colg * 8;
      GLD16(Kh + goffK, (char*)sKh + ldsoff);
      GLD16(Kl + goffK, (char*)sKl + ldsoff);
      const size_t goffV = base + (size_t)row * 2048 + kv0 + colg * 8;
      GLD16(Vt + goffV, (char*)sV + ldsoff);
    }
    asm volatile("s_waitcnt vmcnt(0)" ::: "memory");
    __syncthreads();

    // QK^T (3-term split) -> 16x64 scores per wave
    f32x4 sacc[4];
#pragma unroll
    for (int t = 0; t < 4; t++) sacc[t] = (f32x4){0.f, 0.f, 0.f, 0.f};
#pragma unroll
    for (int cc = 0; cc < 2; cc++) {
      const int sw = cc ? sw1 : sw0;
#pragma unroll
      for (int t = 0; t < 4; t++) {
        const int kr = (t * 16 + c) * 64 + sw;
        short8 kh8 = *(const short8*)&sKh[kr];
        short8 kl8 = *(const short8*)&sKl[kr];
        sacc[t] = MFMA_BF16(qh[cc], kh8, sacc[t]);
        sacc[t] = MFMA_BF16(qh[cc], kl8, sacc[t]);
        sacc[t] = MFMA_BF16(ql[cc], kh8, sacc[t]);
      }
    }

    // mask, scale, online softmax
    float lg[4][4];  // [t][r]
    float tmax[4];
#pragma unroll
    for (int r = 0; r < 4; r++) tmax[r] = -INFINITY;
#pragma unroll
    for (int t = 0; t < 4; t++)
#pragma unroll
      for (int r = 0; r < 4; r++) {
        float s = sacc[t][r];
        if (s == 0.0f) s = -1e9f;   // reference's zero-value mask
        s *= 8.0f;                  // * sqrt(d_k)
        lg[t][r] = s;
        tmax[r] = fmaxf(tmax[r], s);
      }
#pragma unroll
    for (int r = 0; r < 4; r++) {
#pragma unroll
      for (int off = 8; off >= 1; off >>= 1)
        tmax[r] = fmaxf(tmax[r], __shfl_xor(tmax[r], off, 16));
    }
    float scale[4], rsum[4];
#pragma unroll
    for (int r = 0; r < 4; r++) {
      const float mnew = fmaxf(m_run[r], tmax[r]);
      scale[r] = __expf(m_run[r] - mnew);
      m_run[r] = mnew;
      float rs = 0.f;
#pragma unroll
      for (int t = 0; t < 4; t++) {
        lg[t][r] = __expf(lg[t][r] - mnew);
        rs += lg[t][r];
      }
      rsum[r] = rs;
    }
#pragma unroll
    for (int r = 0; r < 4; r++) {
#pragma unroll
      for (int off = 8; off >= 1; off >>= 1)
        rsum[r] += __shfl_xor(rsum[r], off, 16);
      l_run[r] = l_run[r] * scale[r] + rsum[r];
    }
#pragma unroll
    for (int dt = 0; dt < 4; dt++)
#pragma unroll
      for (int r = 0; r < 4; r++) zacc[dt][r] *= scale[r];

    // write P (bf16) to per-wave LDS, swizzled: (row,col) -> row*64 + ((col>>3)^(row&7))*8 + (col&7)
#pragma unroll
    for (int t = 0; t < 4; t++)
#pragma unroll
      for (int r = 0; r < 4; r++) {
        const int row = g * 4 + r;
        const int col = t * 16 + c;
        sP[w][row * 64 + (((col >> 3) ^ (row & 7)) * 8) + (col & 7)] = f2bf(lg[t][r]);
      }
    asm volatile("s_waitcnt lgkmcnt(0)" ::: "memory");

    // PV: A = P row c (k = cc*32+g*8+j), B = Vt row dt*16+c (k contiguous)
#pragma unroll
    for (int cc = 0; cc < 2; cc++) {
      const int sw = cc ? sw1 : sw0;
      short8 pa = *(const short8*)&sP[w][c * 64 + sw];
#pragma unroll
      for (int dt = 0; dt < 4; dt++) {
        short8 vb = *(const short8*)&sV[(dt * 16 + c) * 64 + sw];
        zacc[dt] = MFMA_BF16(pa, vb, zacc[dt]);
      }
    }
  }

  // epilogue: normalize, store Z[b*2048+q][h*64+d] bf16
  float inv[4];
#pragma unroll
  for (int r = 0; r < 4; r++) inv[r] = l_run[r] > 0.f ? 1.0f / l_run[r] : 0.f;
#pragma unroll
  for (int dt = 0; dt < 4; dt++)
#pragma unroll
    for (int r = 0; r < 4; r++) {
      const int qg = qblk * 64 + w * 16 + g * 4 + r;
      const int col = h * 64 + dt * 16 + c;
      Z[(size_t)(b * 2048 + qg) * 1024 + col] = f2bf(zacc[dt][r] * inv[r]);
    }
}

// ---------- output projection GEMM ----------
// out[m,n] = sum_k Z[m,k]*Wo[n,k] + bo[n], M=8192, N=1024, K=1024, fp32 out
__global__ __launch_bounds__(256) void gemm_out(
    const short* __restrict__ Zb, const short* __restrict__ Wob,
    const float* __restrict__ bo, float* __restrict__ out) {
  __shared__ short sA[128 * 32], sB[128 * 32];
  const int tid = threadIdx.x, lane = tid & 63, w = tid >> 6;
  const int wr = w >> 1, wc = w & 1;
  const int g = lane >> 4, c = lane & 15;
  const int m0 = blockIdx.y * 128, n0 = blockIdx.x * 128;

  f32x4 acc[4][4];
#pragma unroll
  for (int i = 0; i < 4; i++)
#pragma unroll
    for (int j = 0; j < 4; j++) acc[i][j] = (f32x4){0.f, 0.f, 0.f, 0.f};

  for (int ks = 0; ks < 32; ks++) {
    const int k0 = ks * 32;
    __syncthreads();
#pragma unroll
    for (int i = 0; i < 2; i++) {
      const int chunk = i * 256 + w * 64 + lane;
      const int row = chunk >> 2;
      const int col = (chunk & 3) * 8;
      const size_t aoff = (size_t)(m0 + row) * 1024 + k0 + col;
      const size_t boff = (size_t)(n0 + row) * 1024 + k0 + col;
      const int ldsoff = (i * 256 + w * 64) * 16;
      GLD16(Zb + aoff, (char*)sA + ldsoff);
      GLD16(Wob + boff, (char*)sB + ldsoff);
    }
    asm volatile("s_waitcnt vmcnt(0)" ::: "memory");
    __syncthreads();

    short8 a[4], b8[4];
#pragma unroll
    for (int i = 0; i < 4; i++) {
      a[i] = *(const short8*)&sA[(wr * 64 + i * 16 + c) * 32 + g * 8];
      b8[i] = *(const short8*)&sB[(wc * 64 + i * 16 + c) * 32 + g * 8];
    }
#pragma unroll
    for (int i = 0; i < 4; i++)
#pragma unroll
      for (int j = 0; j < 4; j++) acc[i][j] = MFMA_BF16(a[i], b8[j], acc[i][j]);
  }

#pragma unroll
  for (int i = 0; i < 4; i++)
#pragma unroll
    for (int j = 0; j < 4; j++)
#pragma unroll
      for (int r = 0; r < 4; r++) {
        const int m = m0 + wr * 64 + i * 16 + g * 4 + r;
        const int n = n0 + wc * 64 + j * 16 + c;
        out[(size_t)m * 1024 + n] = acc[i][j][r] + bo[n];
      }
}

// ---------- host ----------
extern "C" void kernel_launch(void* const* d_in, const int* in_sizes, int n_in,
                              void* d_out, int out_size, void* d_ws, size_t ws_size,
                              hipStream_t stream) {
  const float* x  = (const float*)d_in[0];
  const float* Wq = (const float*)d_in[1];
  const float* Wk = (const float*)d_in[2];
  const float* Wv = (const float*)d_in[3];
  const float* Wo = (const float*)d_in[4];
  const float* bo = (const float*)d_in[5];
  float* out = (float*)d_out;

  const size_t NX = 8388608;   // B*S*D_MODEL
  const size_t NW = 1048576;   // per-projection weight elements
  const size_t NQ = 8388608;   // B*H*S*D_K

  char* p = (char*)d_ws;
  auto take = [&](size_t bytes) -> char* {
    char* r = p;
    p += (bytes + 255) & ~(size_t)255;
    return r;
  };
  short* xh  = (short*)take(NX * 2);
  short* xl  = (short*)take(NX * 2);
  short* Wh  = (short*)take(3 * NW * 2);
  short* Wl  = (short*)take(3 * NW * 2);
  short* Woh = (short*)take(NW * 2);
  short* Qh  = (short*)take(NQ * 2);
  short* Ql  = (short*)take(NQ * 2);
  short* Kh  = (short*)take(NQ * 2);
  short* Kl  = (short*)take(NQ * 2);
  short* Vt  = (short*)take(NQ * 2);
  short* Zb  = (short*)take(NQ * 2);

  split_pair<<<dim3((int)(NX / 256)), 256, 0, stream>>>(x, xh, xl, (int)NX);
  split_pair<<<dim3((int)(NW / 256)), 256, 0, stream>>>(Wq, Wh, Wl, (int)NW);
  split_pair<<<dim3((int)(NW / 256)), 256, 0, stream>>>(Wk, Wh + NW, Wl + NW, (int)NW);
  split_pair<<<dim3((int)(NW / 256)), 256, 0, stream>>>(Wv, Wh + 2 * NW, Wl + 2 * NW, (int)NW);
  cast_bf16<<<dim3((int)(NW / 256)), 256, 0, stream>>>(Wo, Woh, (int)NW);

  gemm_proj<<<dim3(24, 64), 256, 0, stream>>>(xh, xl, Wh, Wl, Qh, Ql, Kh, Kl, Vt);
  attn_kernel<<<dim3(32, 64), 256, 0, stream>>>(Qh, Ql, Kh, Kl, Vt, Zb);
  gemm_out<<<dim3(8, 64), 256, 0, stream>>>(Zb, Woh, bo, out);
}